// Round 2
// baseline (202.428 us; speedup 1.0000x reference)
//
#include <hip/hip_runtime.h>
#include <math.h>

#define DIM    256
#define NBINS  32
#define NK     33        // knots per dim
#define KSTR   65        // padded LDS stride (bank = (k + dloc) % 32)
#define MINW   1e-3f
#define MINH   1e-3f
#define MIND   1e-3f

// ---------------------------------------------------------------------------
// Kernel 1: build per-dim knot tables, transposed [knot][dim] for coalesced
// staging in the main kernel. One wave per dim (lanes 0..31 = bins).
// ---------------------------------------------------------------------------
__global__ __launch_bounds__(256) void spline_tables(
    const float* __restrict__ width,    // [DIM][NBINS]
    const float* __restrict__ height,   // [DIM][NBINS]
    const float* __restrict__ deriv,    // [DIM][NBINS-1]
    float* __restrict__ g_cw,           // [NK][DIM]
    float* __restrict__ g_ch,           // [NK][DIM]
    float* __restrict__ g_dv)           // [NK][DIM]
{
    const int lane = threadIdx.x & 63;
    const int wv   = threadIdx.x >> 6;
    const int d    = blockIdx.x * 4 + wv;
    const int i    = lane & 31;         // bin index (lanes 32..63 mirror)

    // --- widths -> cumwidths ---
    {
        float v = width[d * NBINS + i];
        float m = v;
        #pragma unroll
        for (int o = 16; o >= 1; o >>= 1) m = fmaxf(m, __shfl_xor(m, o, 32));
        float e = __expf(v - m);
        float s = e;
        #pragma unroll
        for (int o = 16; o >= 1; o >>= 1) s += __shfl_xor(s, o, 32);
        float sz = fmaf(e / s, 1.f - MINW * NBINS, MINW);
        float c = sz;                    // inclusive prefix sum over 32 lanes
        #pragma unroll
        for (int o = 1; o < 32; o <<= 1) {
            float n = __shfl_up(c, o, 32);
            if (i >= o) c += n;
        }
        if (lane < 32) {
            if (i == 0) g_cw[0 * DIM + d] = 0.f;
            g_cw[(i + 1) * DIM + d] = (i == 31) ? 1.f : c;
        }
    }
    // --- heights -> cumheights ---
    {
        float v = height[d * NBINS + i];
        float m = v;
        #pragma unroll
        for (int o = 16; o >= 1; o >>= 1) m = fmaxf(m, __shfl_xor(m, o, 32));
        float e = __expf(v - m);
        float s = e;
        #pragma unroll
        for (int o = 16; o >= 1; o >>= 1) s += __shfl_xor(s, o, 32);
        float sz = fmaf(e / s, 1.f - MINH * NBINS, MINH);
        float c = sz;
        #pragma unroll
        for (int o = 1; o < 32; o <<= 1) {
            float n = __shfl_up(c, o, 32);
            if (i >= o) c += n;
        }
        if (lane < 32) {
            if (i == 0) g_ch[0 * DIM + d] = 0.f;
            g_ch[(i + 1) * DIM + d] = (i == 31) ? 1.f : c;
        }
    }
    // --- derivatives (boundary == 1 exactly: MIND + softplus(log(expm1(1-MIND)))) ---
    if (lane < 32) {
        if (i == 0) { g_dv[0 * DIM + d] = 1.f; g_dv[32 * DIM + d] = 1.f; }
        if (i < 31) {
            float u  = deriv[d * (NBINS - 1) + i];
            float sp = fmaxf(u, 0.f) + log1pf(__expf(-fabsf(u)));   // stable softplus
            g_dv[(i + 1) * DIM + d] = MIND + sp;
        }
    }
}

// ---------------------------------------------------------------------------
// Kernel 2: bulk spline evaluation. Block = 256 threads, owns a 64-dim tile
// (tables staged in LDS) and iterates over 16-row groups. float4 x/y/ld.
// ---------------------------------------------------------------------------
__global__ __launch_bounds__(256) void spline_main(
    const float* __restrict__ x,
    const float* __restrict__ g_cw,
    const float* __restrict__ g_ch,
    const float* __restrict__ g_dv,
    float* __restrict__ yo,
    float* __restrict__ ldo,
    int nrg)                            // number of 16-row groups = rows/16
{
    __shared__ float s_cw[NK * KSTR];
    __shared__ float s_ch[NK * KSTR];
    __shared__ float s_dv[NK * KSTR];

    const int tile = blockIdx.x & 3;    // 4 dim-tiles of 64
    const int rb   = blockIdx.x >> 2;   // row-group start
    const int nrb  = gridDim.x  >> 2;   // row-group stride
    const int d0   = tile * 64;

    for (int f = threadIdx.x; f < NK * 64; f += 256) {
        int k = f >> 6, dl = f & 63;
        s_cw[k * KSTR + dl] = g_cw[k * DIM + d0 + dl];
        s_ch[k * KSTR + dl] = g_ch[k * DIM + d0 + dl];
        s_dv[k * KSTR + dl] = g_dv[k * DIM + d0 + dl];
    }
    __syncthreads();

    const int tg   = threadIdx.x & 15;  // dim-subgroup within tile
    const int rg   = threadIdx.x >> 4;  // row within 16-row group
    const int dloc = tg * 4;

    for (int g = rb; g < nrg; g += nrb) {
        const int row  = g * 16 + rg;
        const int base = row * DIM + d0 + dloc;
        float4 xv = *reinterpret_cast<const float4*>(x + base);
        float xs[4] = {xv.x, xv.y, xv.z, xv.w};
        float ys[4], ls[4];
        #pragma unroll
        for (int j = 0; j < 4; ++j) {
            const int dl = dloc + j;
            const float xo = xs[j];
            const float xc = fminf(fmaxf(xo, 0.f), 1.f);
            // binary search: largest b in [0,31] with cw[b] <= xc
            int b = 0;
            if (s_cw[16 * KSTR + dl]      <= xc) b = 16;
            if (s_cw[(b + 8) * KSTR + dl] <= xc) b += 8;
            if (s_cw[(b + 4) * KSTR + dl] <= xc) b += 4;
            if (s_cw[(b + 2) * KSTR + dl] <= xc) b += 2;
            if (s_cw[(b + 1) * KSTR + dl] <= xc) b += 1;

            const float cwb  = s_cw[b * KSTR + dl];
            const float cwb1 = s_cw[(b + 1) * KSTR + dl];
            const float chb  = s_ch[b * KSTR + dl];
            const float chb1 = s_ch[(b + 1) * KSTR + dl];
            const float db   = s_dv[b * KSTR + dl];
            const float db1  = s_dv[(b + 1) * KSTR + dl];

            const float w     = cwb1 - cwb;
            const float h     = chb1 - chb;
            const float invw  = __builtin_amdgcn_rcpf(w);
            const float delta = h * invw;
            const float theta = (xc - cwb) * invw;
            const float omt   = 1.f - theta;
            const float t1m   = theta * omt;
            const float tt    = theta * theta;

            const float num  = h * fmaf(delta, tt, db * t1m);
            const float den  = fmaf(fmaf(-2.f, delta, db + db1), t1m, delta);
            const float dinv = __builtin_amdgcn_rcpf(den);
            const float yin  = fmaf(num, dinv, chb);

            const float inner = fmaf(db1, tt, fmaf(2.f * delta, t1m, db * omt * omt));
            const float dn    = delta * delta * inner;
            const float ldin  = __logf(dn * dinv * dinv);   // log(dn) - 2log(den)

            const bool inside = (xo >= 0.f) && (xo <= 1.f);
            ys[j] = inside ? yin : xo;
            ls[j] = inside ? ldin : 0.f;
        }
        *reinterpret_cast<float4*>(yo  + base) = make_float4(ys[0], ys[1], ys[2], ys[3]);
        *reinterpret_cast<float4*>(ldo + base) = make_float4(ls[0], ls[1], ls[2], ls[3]);
    }
}

// ---------------------------------------------------------------------------
extern "C" void kernel_launch(void* const* d_in, const int* in_sizes, int n_in,
                              void* d_out, int out_size, void* d_ws, size_t ws_size,
                              hipStream_t stream) {
    const float* x      = (const float*)d_in[0];
    const float* width  = (const float*)d_in[1];
    const float* height = (const float*)d_in[2];
    const float* deriv  = (const float*)d_in[3];

    const int total = in_sizes[0];      // B * DIM
    const int rows  = total / DIM;
    const int nrg   = rows >> 4;        // 16-row groups

    float* out  = (float*)d_out;
    float* yp   = out;                  // y:      [B][DIM]
    float* lp   = out + total;          // logdet: [B][DIM]

    float* g_cw = (float*)d_ws;         // [NK][DIM]
    float* g_ch = g_cw + NK * DIM;
    float* g_dv = g_ch + NK * DIM;      // total 3*33*256*4 = 101376 B of ws

    spline_tables<<<DIM / 4, 256, 0, stream>>>(width, height, deriv, g_cw, g_ch, g_dv);
    spline_main<<<2048, 256, 0, stream>>>(x, g_cw, g_ch, g_dv, yp, lp, nrg);
}

// Round 4
// 197.874 us; speedup vs baseline: 1.0230x; 1.0230x over previous
//
#include <hip/hip_runtime.h>
#include <math.h>

#define DIM    256
#define NBINS  32
#define NK     33        // knots per dim
#define KSTR   65        // padded LDS stride: bank = (k + slot) % 32
#define MINW   1e-3f
#define MINH   1e-3f
#define MIND   1e-3f

// dim-within-tile -> LDS slot permutation. Thread tg owns dims 4tg..4tg+3;
// slot(4tg+j) = 16j+tg, so a fixed-knot probe hits 16 distinct banks with a
// 4-way same-address broadcast (free) instead of 8-way conflicts.
__device__ __forceinline__ int slot_of(int dl) { return ((dl & 3) << 4) | (dl >> 2); }

// ---------------------------------------------------------------------------
// Kernel 1: build per-dim knot tables, transposed [knot][dim] for coalesced
// staging in the main kernel. One wave per dim (lanes 0..31 = bins).
// ---------------------------------------------------------------------------
__global__ __launch_bounds__(256) void spline_tables(
    const float* __restrict__ width,    // [DIM][NBINS]
    const float* __restrict__ height,   // [DIM][NBINS]
    const float* __restrict__ deriv,    // [DIM][NBINS-1]
    float* __restrict__ g_cw,           // [NK][DIM]
    float* __restrict__ g_ch,           // [NK][DIM]
    float* __restrict__ g_dv)           // [NK][DIM]
{
    const int lane = threadIdx.x & 63;
    const int wv   = threadIdx.x >> 6;
    const int d    = blockIdx.x * 4 + wv;
    const int i    = lane & 31;         // bin index (lanes 32..63 mirror)

    // --- widths -> cumwidths ---
    {
        float v = width[d * NBINS + i];
        float m = v;
        #pragma unroll
        for (int o = 16; o >= 1; o >>= 1) m = fmaxf(m, __shfl_xor(m, o, 32));
        float e = __expf(v - m);
        float s = e;
        #pragma unroll
        for (int o = 16; o >= 1; o >>= 1) s += __shfl_xor(s, o, 32);
        float sz = fmaf(e / s, 1.f - MINW * NBINS, MINW);
        float c = sz;                    // inclusive prefix sum over 32 lanes
        #pragma unroll
        for (int o = 1; o < 32; o <<= 1) {
            float n = __shfl_up(c, o, 32);
            if (i >= o) c += n;
        }
        if (lane < 32) {
            if (i == 0) g_cw[0 * DIM + d] = 0.f;
            g_cw[(i + 1) * DIM + d] = (i == 31) ? 1.f : c;
        }
    }
    // --- heights -> cumheights ---
    {
        float v = height[d * NBINS + i];
        float m = v;
        #pragma unroll
        for (int o = 16; o >= 1; o >>= 1) m = fmaxf(m, __shfl_xor(m, o, 32));
        float e = __expf(v - m);
        float s = e;
        #pragma unroll
        for (int o = 16; o >= 1; o >>= 1) s += __shfl_xor(s, o, 32);
        float sz = fmaf(e / s, 1.f - MINH * NBINS, MINH);
        float c = sz;
        #pragma unroll
        for (int o = 1; o < 32; o <<= 1) {
            float n = __shfl_up(c, o, 32);
            if (i >= o) c += n;
        }
        if (lane < 32) {
            if (i == 0) g_ch[0 * DIM + d] = 0.f;
            g_ch[(i + 1) * DIM + d] = (i == 31) ? 1.f : c;
        }
    }
    // --- derivatives (boundary == 1 exactly: MIND + softplus(log(expm1(1-MIND)))) ---
    if (lane < 32) {
        if (i == 0) { g_dv[0 * DIM + d] = 1.f; g_dv[32 * DIM + d] = 1.f; }
        if (i < 31) {
            float u  = deriv[d * (NBINS - 1) + i];
            float sp = fmaxf(u, 0.f) + log1pf(__expf(-fabsf(u)));   // stable softplus
            g_dv[(i + 1) * DIM + d] = MIND + sp;
        }
    }
}

// ---------------------------------------------------------------------------
// Kernel 2: bulk spline evaluation. Block = 256 threads, owns a 64-dim tile
// (tables staged in LDS, slot-permuted) and iterates over 16-row groups.
// Grid = 1536 = 6 blocks/CU exactly resident (LDS 25.7 KB -> 6/CU).
// ---------------------------------------------------------------------------
__global__ __launch_bounds__(256, 6) void spline_main(
    const float* __restrict__ x,
    const float* __restrict__ g_cw,
    const float* __restrict__ g_ch,
    const float* __restrict__ g_dv,
    float* __restrict__ yo,
    float* __restrict__ ldo,
    int nrg)                            // number of 16-row groups = rows/16
{
    __shared__ float s_cw[NK * KSTR];
    __shared__ float s_ch[NK * KSTR];
    __shared__ float s_dv[NK * KSTR];

    const int tile = blockIdx.x & 3;    // 4 dim-tiles of 64
    const int rb   = blockIdx.x >> 2;   // row-group start
    const int nrb  = gridDim.x  >> 2;   // row-group stride (384)
    const int d0   = tile * 64;

    for (int f = threadIdx.x; f < NK * 64; f += 256) {
        int k = f >> 6, dl = f & 63;
        int sl = slot_of(dl);           // writes cover a full 0..63 permutation: conflict-free
        s_cw[k * KSTR + sl] = g_cw[k * DIM + d0 + dl];
        s_ch[k * KSTR + sl] = g_ch[k * DIM + d0 + dl];
        s_dv[k * KSTR + sl] = g_dv[k * DIM + d0 + dl];
    }
    __syncthreads();

    const int tg   = threadIdx.x & 15;  // dim-subgroup within tile
    const int rg   = threadIdx.x >> 4;  // row within 16-row group
    const int dloc = tg * 4;

    for (int g = rb; g < nrg; g += nrb) {
        const int row  = g * 16 + rg;
        const int base = row * DIM + d0 + dloc;
        float4 xv = *reinterpret_cast<const float4*>(x + base);
        float xs[4] = {xv.x, xv.y, xv.z, xv.w};
        float ys[4], ls[4];
        #pragma unroll
        for (int j = 0; j < 4; ++j) {
            const int sj = (j << 4) | tg;       // slot of dim dloc+j
            const float xo = xs[j];
            const float xc = fminf(fmaxf(xo, 0.f), 1.f);
            // binary search: largest b in [0,31] with cw[b] <= xc
            int b = 0;
            if (s_cw[16 * KSTR + sj]      <= xc) b = 16;
            if (s_cw[(b + 8) * KSTR + sj] <= xc) b += 8;
            if (s_cw[(b + 4) * KSTR + sj] <= xc) b += 4;
            if (s_cw[(b + 2) * KSTR + sj] <= xc) b += 2;
            if (s_cw[(b + 1) * KSTR + sj] <= xc) b += 1;

            const float cwb  = s_cw[b * KSTR + sj];
            const float cwb1 = s_cw[(b + 1) * KSTR + sj];
            const float chb  = s_ch[b * KSTR + sj];
            const float chb1 = s_ch[(b + 1) * KSTR + sj];
            const float db   = s_dv[b * KSTR + sj];
            const float db1  = s_dv[(b + 1) * KSTR + sj];

            const float w     = cwb1 - cwb;
            const float h     = chb1 - chb;
            const float invw  = __builtin_amdgcn_rcpf(w);
            const float delta = h * invw;
            const float theta = (xc - cwb) * invw;
            const float omt   = 1.f - theta;
            const float t1m   = theta * omt;
            const float tt    = theta * theta;

            const float num  = h * fmaf(delta, tt, db * t1m);
            const float den  = fmaf(fmaf(-2.f, delta, db + db1), t1m, delta);
            const float dinv = __builtin_amdgcn_rcpf(den);
            const float yin  = fmaf(num, dinv, chb);

            const float inner = fmaf(db1, tt, fmaf(2.f * delta, t1m, db * omt * omt));
            const float dn    = delta * delta * inner;
            const float ldin  = __logf(dn * dinv * dinv);   // log(dn) - 2log(den)

            const bool inside = (xo >= 0.f) && (xo <= 1.f);
            ys[j] = inside ? yin : xo;
            ls[j] = inside ? ldin : 0.f;
        }
        *reinterpret_cast<float4*>(yo  + base) = make_float4(ys[0], ys[1], ys[2], ys[3]);
        *reinterpret_cast<float4*>(ldo + base) = make_float4(ls[0], ls[1], ls[2], ls[3]);
    }
}

// ---------------------------------------------------------------------------
extern "C" void kernel_launch(void* const* d_in, const int* in_sizes, int n_in,
                              void* d_out, int out_size, void* d_ws, size_t ws_size,
                              hipStream_t stream) {
    const float* x      = (const float*)d_in[0];
    const float* width  = (const float*)d_in[1];
    const float* height = (const float*)d_in[2];
    const float* deriv  = (const float*)d_in[3];

    const int total = in_sizes[0];      // B * DIM
    const int rows  = total / DIM;
    const int nrg   = rows >> 4;        // 16-row groups

    float* out  = (float*)d_out;
    float* yp   = out;                  // y:      [B][DIM]
    float* lp   = out + total;          // logdet: [B][DIM]

    float* g_cw = (float*)d_ws;         // [NK][DIM]
    float* g_ch = g_cw + NK * DIM;
    float* g_dv = g_ch + NK * DIM;      // total 3*33*256*4 = 101376 B of ws

    spline_tables<<<DIM / 4, 256, 0, stream>>>(width, height, deriv, g_cw, g_ch, g_dv);
    // 1536 = 6 blocks/CU x 256 CU: fully resident, no residency tail.
    spline_main<<<1536, 256, 0, stream>>>(x, g_cw, g_ch, g_dv, yp, lp, nrg);
}